// Round 1
// 244.497 us; speedup vs baseline: 1.0455x; 1.0455x over previous
//
#include <hip/hip_runtime.h>
#include <math.h>

#define L_TOT 4194304   // 2^22 upsampled samples
#define NFR   16384     // frames / f0 length
#define OUTN  4194048   // output length

// ---------- workspace layout (floats) ----------
// [0, L_TOT)                : cumsum tree levels 11..22 (packed; lower levels in LDS)
// [L_TOT, 2*L_TOT)          : pulse signal
// [2*L_TOT + 0,   +512)     : twiddle cos  (cos(2*pi*j/1024))
// [2*L_TOT + 512, +1024)    : twiddle sin
// [2*L_TOT + 1024,+2048)    : hann window (1024) — used by edge finalize
// [2*L_TOT + 2048,+2048+NFR): f0 = exp(log_f0)

__device__ __forceinline__ int lvl_off(int a) {
  return L_TOT - (L_TOT >> (a - 1));
}

// LDS bank swizzle for the 1024-entry float2 FFT buffers.
// Stockham stage-0 writes have e mod 16 = 4(b&3)+j (4 bank-pairs / 16-lane phase),
// stage-1 writes have e mod 16 = (b&3)+4j.  XOR the per-phase entropy (e>>4)&3
// into BOTH halves of the low nibble: injective for both patterns AND for the
// stride-256 reads (low nibble already full-span).  Bijective within [0,1024).
__device__ __forceinline__ int swz(int e) {
  return e ^ (((e >> 4) & 3) * 5);   // 5*h == (h<<2)|h for h<4
}

// linear_interp(exp(log_f0), 256) at position j — matches reference rounding (no FMA)
__device__ __forceinline__ float f0_up_val(const float* f0arr, int j) {
  float pos = __fadd_rn(__fmul_rn(__fadd_rn((float)j, 0.5f), 1.0f / 256.0f), -0.5f);
  pos = fminf(fmaxf(pos, 0.0f), 16383.0f);
  int lo = (int)pos;
  int hi = min(lo + 1, NFR - 1);
  float frac = __fadd_rn(pos, -(float)lo);
  float a = __fmul_rn(f0arr[lo], __fadd_rn(1.0f, -frac));
  float b = __fmul_rn(f0arr[hi], frac);
  return __fadd_rn(a, b);
}

// full prefix sum replicating jax.lax.associative_scan bit-exactly (validated R4-R8).
// Only called with m ≡ 0 or ±1 (mod 4096), or m=1 -> never reads levels 1..10.
__device__ float prefix_sum(const float* W, const float* f0arr, int m) {
  float acc = 0.0f;
  bool first = true;
  int pos = 0;
  for (int a = 22; a >= 1; --a) {
    if (m & (1 << a)) {
      float node = W[lvl_off(a) + (pos >> a)];
      acc = first ? node : __fadd_rn(acc, node);
      first = false;
      pos += (1 << a);
    }
  }
  if (m & 1) {
    float node = f0_up_val(f0arr, pos);
    acc = first ? node : __fadd_rn(acc, node);
  }
  return acc;
}

// ---------- init: twiddles, window, f0 ----------
__global__ __launch_bounds__(256) void init_tables(const float* __restrict__ logf0,
                                                   float* __restrict__ W) {
  int g = blockIdx.x * 256 + threadIdx.x;
  float* twc = W + 2 * L_TOT;
  float* tws = twc + 512;
  float* wh  = twc + 1024;
  float* f0arr = twc + 2048;
  if (g < 512) {
    double a = (double)g * 3.14159265358979323846 / 512.0; // 2*pi*g/1024
    twc[g] = (float)cos(a);
    tws[g] = (float)sin(a);
  }
  if (g < 1024) {
    double a = (double)g * 3.14159265358979323846 / 512.0;
    wh[g] = (float)(0.5 - 0.5 * cos(a));
  }
  if (g >= 2048 && g < 2048 + NFR) {
    f0arr[g - 2048] = (float)exp((double)logf0[g - 2048]); // correctly-rounded expf
  }
}

// ---------- cumsum tree: build levels 1..11, store only level 11 ----------
__global__ __launch_bounds__(256) void tree_kernel(float* W) {
  const float* f0arr = W + 2 * L_TOT + 2048;
  __shared__ float A[2048];
  __shared__ float B[1024];
  int tid = threadIdx.x;
  int base = blockIdx.x * 2048;
  for (int i = tid; i < 2048; i += 256) A[i] = f0_up_val(f0arr, base + i);
  __syncthreads();
  float* src = A;
  float* dst = B;
  int cnt = 1024;
  for (int a = 1; a <= 11; ++a) {
    int gbase = base >> a;
    for (int i = tid; i < cnt; i += 256) {
      float v = __fadd_rn(src[2 * i], src[2 * i + 1]);
      dst[i] = v;
      if (a == 11) W[lvl_off(11) + gbase + i] = v;
    }
    __syncthreads();
    float* tmp = src; src = dst; dst = tmp;
    cnt >>= 1;
  }
}

// ---------- cumsum tree, levels 12..22 ----------
__global__ __launch_bounds__(256) void tree_top_kernel(float* W) {
  __shared__ float A[2048];
  __shared__ float B[1024];
  int tid = threadIdx.x;
  for (int i = tid; i < 2048; i += 256) A[i] = W[lvl_off(11) + i];
  __syncthreads();
  float* src = A;
  float* dst = B;
  int cnt = 1024;
  for (int a = 12; a <= 22; ++a) {
    for (int i = tid; i < cnt; i += 256) {
      float v = __fadd_rn(src[2 * i], src[2 * i + 1]);
      dst[i] = v;
      W[lvl_off(a) + i] = v;
    }
    __syncthreads();
    float* tmp = src; src = dst; dst = tmp;
    cnt >>= 1;
  }
}

// ---------- impulse train v3: 4096 samples/block, 16 per thread ----------
// Three-tier exact fold: low bits (3..0) from per-thread REGISTER pairwise sums,
// mid bits (11..4) from a per-thread LDS-tree walk, top bits (22..12) block-
// uniform. Identical association to prefix_sum -> bit-exact (validated R4-R8).
__global__ __launch_bounds__(256) void pulse_kernel(float* W) {
  const float* f0arr = W + 2 * L_TOT + 2048;
  __shared__ float Tl[510];   // levels 4..11: off(a) = 512 - (512 >> (a-4))
  __shared__ float P[4100];   // P[r] = prefix(base+r), r in [1,4097]
  int tid = threadIdx.x;
  int base = blockIdx.x * 4096;

  float v[16];
#pragma unroll
  for (int c = 0; c < 16; ++c) v[c] = f0_up_val(f0arr, base + 16 * tid + c);
  float s2[8], s4[4], s8[2];
#pragma unroll
  for (int j = 0; j < 8; ++j) s2[j] = __fadd_rn(v[2 * j], v[2 * j + 1]);
#pragma unroll
  for (int j = 0; j < 4; ++j) s4[j] = __fadd_rn(s2[2 * j], s2[2 * j + 1]);
  s8[0] = __fadd_rn(s4[0], s4[1]);
  s8[1] = __fadd_rn(s4[2], s4[3]);
  Tl[tid] = __fadd_rn(s8[0], s8[1]);          // level-4 leaf (s16)
  __syncthreads();
  if (tid < 128) Tl[256 + tid] = __fadd_rn(Tl[2 * tid], Tl[2 * tid + 1]);
  __syncthreads();
  if (tid < 64)  Tl[384 + tid] = __fadd_rn(Tl[256 + 2 * tid], Tl[256 + 2 * tid + 1]);
  __syncthreads();
  if (tid < 32)  Tl[448 + tid] = __fadd_rn(Tl[384 + 2 * tid], Tl[384 + 2 * tid + 1]);
  __syncthreads();
  if (tid < 16)  Tl[480 + tid] = __fadd_rn(Tl[448 + 2 * tid], Tl[448 + 2 * tid + 1]);
  __syncthreads();
  if (tid < 8)   Tl[496 + tid] = __fadd_rn(Tl[480 + 2 * tid], Tl[480 + 2 * tid + 1]);
  __syncthreads();
  if (tid < 4)   Tl[504 + tid] = __fadd_rn(Tl[496 + 2 * tid], Tl[496 + 2 * tid + 1]);
  __syncthreads();
  if (tid < 2)   Tl[508 + tid] = __fadd_rn(Tl[504 + 2 * tid], Tl[504 + 2 * tid + 1]);
  __syncthreads();

  // top fold (levels 22..12 of base) — block-uniform broadcast loads
  float accT = 0.0f;
  bool firstT = true;
  {
    int pos = 0;
    for (int a = 22; a >= 12; --a) {
      if (base & (1 << a)) {
        float node = W[lvl_off(a) + (pos >> a)];
        accT = firstT ? node : __fadd_rn(accT, node);
        firstT = false;
        pos += (1 << a);
      }
    }
  }
  // mid fold (levels 11..4 of r_hi = 16*tid) — once per thread
  float accM = accT;
  bool firstM = firstT;
  {
    int rh = 16 * tid;
    int lpos = 0;
    for (int a = 11; a >= 4; --a) {
      if (rh & (1 << a)) {
        float node = Tl[512 - (512 >> (a - 4)) + (lpos >> a)];
        accM = firstM ? node : __fadd_rn(accM, node);
        firstM = false;
        lpos += (1 << a);
      }
    }
  }
  if (tid >= 1) P[16 * tid] = accM;          // prefix(base+16t): no low bits
  // low fold (bits 3..0 of c) — register sums only
#pragma unroll
  for (int c = 1; c <= 15; ++c) {
    float acc = accM;
    bool first = firstM;
    int lp = 0;
    if (c & 8) { float n = s8[lp >> 3]; acc = first ? n : __fadd_rn(acc, n); first = false; lp += 8; }
    if (c & 4) { float n = s4[lp >> 2]; acc = first ? n : __fadd_rn(acc, n); first = false; lp += 4; }
    if (c & 2) { float n = s2[lp >> 1]; acc = first ? n : __fadd_rn(acc, n); first = false; lp += 2; }
    if (c & 1) { float n = v[lp];       acc = first ? n : __fadd_rn(acc, n); }
    P[16 * tid + c] = acc;
  }
  if (tid == 0) P[4096] = prefix_sum(W, f0arr, base + 4096);
  if (tid == 1) {
    int m2 = base + 4097;
    P[4097] = (m2 <= L_TOT) ? prefix_sum(W, f0arr, m2) : 0.0f;
  }
  __syncthreads();

  float o[16];
#pragma unroll
  for (int c = 0; c < 16; ++c) {
    int i = base + 16 * tid + c;
    float P1 = P[16 * tid + c + 1];
    float P2 = (i == L_TOT - 1) ? prefix_sum(W, f0arr, 1)  // roll(-1) wrap
                                : P[16 * tid + c + 2];
    float t1 = __fdiv_rn(P1, 24000.0f);
    float saw1 = __fadd_rn(t1, -floorf(t1));
    float t2 = __fdiv_rn(P2, 24000.0f);
    float saw2 = __fadd_rn(t2, -floorf(t2));
    float cc = __fdiv_rn(v[c], 24000.0f);
    o[c] = __fadd_rn(__fadd_rn(saw1, -saw2), cc);
  }
#pragma unroll
  for (int k = 0; k < 4; ++k)
    *(float4*)&W[L_TOT + base + 16 * tid + 4 * k] =
        make_float4(o[4 * k], o[4 * k + 1], o[4 * k + 2], o[4 * k + 3]);
}

// ---------- Stockham radix-4 FFT, N=1024, 256 threads, quarter twiddle table ----------
// tw[0..256] holds w^t = (cos,sin)(2*pi*t/1024) for t<=256; t = tid&~(m-1) <= 255.
// v = w^{2t} = u^2, w^{3t} = u*v derived in registers (~1e-7 rounding, within tol).
// All S/D indices pass through swz() -> bank-conflict-free stage-0/1 writes.
// Result lands in Pb after 5 stages.
template <int DIR>
__device__ void fft1024_r4(float2* X, float2* Pb, const float2* tw) {
  int tid = threadIdx.x;
  float2* S = X;
  float2* D = Pb;
  __syncthreads();
#pragma unroll
  for (int s = 0; s < 5; ++s) {
    int m = 1 << (2 * s);
    int b = tid;
    int t = b & ~(m - 1);
    float2 twu = tw[t];
    float ur = twu.x, ui = (DIR > 0) ? twu.y : -twu.y;
    float vr = ur * ur - ui * ui;       // w^{2t} = u^2
    float vi = 2.0f * ur * ui;
    float w3r = ur * vr - ui * vi;      // w^{3t} = u*v
    float w3i = ur * vi + ui * vr;
    float2 x0 = S[swz(b)], x1 = S[swz(b + 256)], x2 = S[swz(b + 512)], x3 = S[swz(b + 768)];
    float s0r = x0.x + x2.x, s0i = x0.y + x2.y;
    float s1r = x1.x + x3.x, s1i = x1.y + x3.y;
    float d0r = x0.x - x2.x, d0i = x0.y - x2.y;
    float e1r = x1.x - x3.x, e1i = x1.y - x3.y;
    float ser = (DIR > 0) ? -e1i : e1i;   // DIR*i*(x1-x3)
    float sei = (DIR > 0) ? e1r : -e1r;
    int d0 = b + 3 * t;                 // 4jm + k
    D[swz(d0)] = make_float2(s0r + s1r, s0i + s1i);
    float t1r = d0r + ser, t1i = d0i + sei;
    D[swz(d0 + m)] = make_float2(t1r * ur - t1i * ui, t1r * ui + t1i * ur);
    float t2r = s0r - s1r, t2i = s0i - s1i;
    D[swz(d0 + 2 * m)] = make_float2(t2r * vr - t2i * vi, t2r * vi + t2i * vr);
    float t3r = d0r - ser, t3i = d0i - sei;
    D[swz(d0 + 3 * m)] = make_float2(t3r * w3r - t3i * w3i, t3r * w3i + t3i * w3r);
    __syncthreads();
    float2* tmp = S; S = D; D = tmp;
  }
}

// Hann from quarter table: w(i) = 0.5 - 0.5*cos(2*pi*i/1024)
// mirror: i>512 -> 1024-i; j in (256,512] -> cos = -tw[512-j].x; tw[256].x == 0.
__device__ __forceinline__ float hann_w(int i, const float2* tw) {
  int j = (i > 512) ? (1024 - i) : i;
  float c = (j <= 256) ? tw[j].x : -tw[512 - j].x;
  return 0.5f - 0.5f * c;
}

// spectral combine for one bin: H[k] <- Sp[k]*H[k] + Sn[k]*An   (Y is swizzled)
__device__ __forceinline__ void combine_one(int k, float An, const float2* Y, float2* H) {
  int k2 = (1024 - k) & 1023;
  float2 z = Y[swz(k)], mm = Y[swz(k2)];
  float Ar = 0.5f * (z.x + mm.x), Ai = 0.5f * (z.y - mm.y);  // even (noise) part
  float Br = 0.5f * (z.y + mm.y), Bi = 0.5f * (mm.x - z.x);  // odd (pulse) part
  float2 h = H[k];
  H[k] = make_float2(Br * h.x - Bi * h.y + Ar * An,
                     Br * h.y + Bi * h.x + Ai * An);
}

// ---------- per-block fused kernel: TWO adjacent frames, 5 FFTs (validated R7/R8) ----------
// LDS 26648 B -> 6 blocks/CU. OLA pre-scaled by 1/1536 (interior wsq==1.5).
// Frames A and B overlap by 768 samples: their OLA contributions are summed
// in-register first -> 1280 atomics/block instead of 2048.
__global__ __launch_bounds__(256) void column_kernel(
    const float* __restrict__ noise,
    const float* __restrict__ envn,
    const float* __restrict__ envp,
    const float* __restrict__ W,
    float* __restrict__ out) {
  __shared__ float2 F[1024], Y[1024];    // FFT ping-pong (input in F, result in Y)
  __shared__ float2 hA[513], hB[513];
  __shared__ float2 tw[257];
  int tid = threadIdx.x;
  int bid = blockIdx.x;
  // XCD swizzle: each XCD streams a contiguous frame range (env L2 locality).
  int g = (bid & 7) * 1024 + (bid >> 3);
  int fA = 2 * g;                        // frames fA, fA+1
  const float* pulse = W + L_TOT;
  const float* gtab = W + 2 * L_TOT;

  for (int i = tid; i < 257; i += 256) tw[i] = make_float2(gtab[i], gtab[512 + i]);
  for (int k = tid; k < 513; k += 256) {
    float2 e = *(const float2*)&envp[k * NFR + fA];   // fA even -> 8B aligned
    hA[k] = e;                                        // (log ampA, log ampB)
  }
  __syncthreads();

  // ---- (1) packed cepstrum: z = envA_sym + i*envB_sym (both real even) ----
  for (int i = tid; i < 1024; i += 256) {
    int k = (i <= 512) ? i : 1024 - i;
    F[swz(i)] = hA[k];
  }
  fft1024_r4<+1>(F, Y, tw);
  // cep fold: scales 2^-10 / 2^-9 are exact; identical rounding to R5-R8
  {
    float2 a0 = Y[swz(tid)], a1 = Y[swz(tid + 256)], a2 = Y[swz(tid + 512)];
    float s0 = (tid == 0) ? (1.0f / 1024.0f) : (2.0f / 1024.0f);
    F[swz(tid)] = make_float2(a0.x * s0, a0.y * s0);
    F[swz(tid + 256)] = make_float2(a1.x * (2.0f / 1024.0f), a1.y * (2.0f / 1024.0f));
    F[swz(tid + 512)] = (tid == 0) ? make_float2(a2.x * (1.0f / 1024.0f),
                                                 a2.y * (1.0f / 1024.0f))
                                   : make_float2(0.0f, 0.0f);
    F[swz(tid + 768)] = make_float2(0.0f, 0.0f);
  }
  // ---- (2) packed rfft of two real cepstra; hermitian unpack; H=exp ----
  fft1024_r4<-1>(F, Y, tw);
  for (int k = tid; k < 513; k += 256) {
    int k2 = (1024 - k) & 1023;
    float2 z = Y[swz(k)], mm = Y[swz(k2)];
    float GAr = 0.5f * (z.x + mm.x), GAi = 0.5f * (z.y - mm.y);
    float GBr = 0.5f * (z.y + mm.y), GBi = 0.5f * (mm.x - z.x);
    float er = expf(GAr);
    float si, co;
    sincosf(GAi, &si, &co);
    hA[k] = make_float2(er * co, er * si);
    er = expf(GBr);
    sincosf(GBi, &si, &co);
    hB[k] = make_float2(er * co, er * si);
  }

  // ---- (3) frame A: pack z = noise + i*pulse (windowed, reflect-padded) ----
  for (int i = tid; i < 1024; i += 256) {
    int q = 256 * fA - 256 + i;
    if (q < 0) q = -q;
    else if (q >= L_TOT) q = 2 * L_TOT - 2 - q;
    float wv = hann_w(i, tw);
    F[swz(i)] = make_float2(noise[q] * wv, pulse[q] * wv);
  }
  fft1024_r4<-1>(F, Y, tw);
  float2 eA0 = *(const float2*)&envn[tid * NFR + fA];
  combine_one(tid, expf(eA0.x), Y, hA);
  float2 eA1 = *(const float2*)&envn[(tid + 256) * NFR + fA];
  combine_one(tid + 256, expf(eA1.x), Y, hA);
  float2 eA2 = make_float2(0.0f, 0.0f);
  if (tid == 0) {
    eA2 = *(const float2*)&envn[512 * NFR + fA];
    combine_one(512, expf(eA2.x), Y, hA);
  }

  // ---- (4) frame B ----
  for (int i = tid; i < 1024; i += 256) {
    int q = 256 * fA + i;                     // frame fA+1 start - 256 (q >= 0)
    if (q >= L_TOT) q = 2 * L_TOT - 2 - q;
    float wv = hann_w(i, tw);
    F[swz(i)] = make_float2(noise[q] * wv, pulse[q] * wv);
  }
  fft1024_r4<-1>(F, Y, tw);
  combine_one(tid, expf(eA0.y), Y, hB);
  combine_one(tid + 256, expf(eA1.y), Y, hB);
  if (tid == 0) combine_one(512, expf(eA2.y), Y, hB);
  __syncthreads();   // hA/hB must be visible cross-thread below

  // ---- (5) packed hermitian inverse: Z = YA_full + i*YB_full ----
  for (int i = tid; i < 1024; i += 256) {
    if (i <= 512) {
      F[swz(i)] = make_float2(hA[i].x - hB[i].y, hA[i].y + hB[i].x);
    } else {
      int j = 1024 - i;
      F[swz(i)] = make_float2(hA[j].x + hB[j].y, hB[j].x - hA[j].y);
    }
  }
  fft1024_r4<+1>(F, Y, tw);
  // fused OLA over the combined 1280-sample span: ya(i) + yb(i-256)
  const float sc = 1.0f / 1536.0f;   // 1/1024 FFT scale * 1/1.5 wsq
  for (int i = tid; i < 1280; i += 256) {
    float val = 0.0f;
    if (i < 1024) val = Y[swz(i)].x * (hann_w(i, tw) * sc);
    if (i >= 256) {
      int j = i - 256;
      val += Y[swz(j)].y * (hann_w(j, tw) * sc);
    }
    int t = 256 * fA - 512 + i;
    if (t >= 0 && t < OUTN) atomicAdd(&out[t], val);
  }
}

// ---------- edge fix-up: first/last 256 samples have <4 window terms ----------
__global__ __launch_bounds__(256) void finalize_kernel(float* __restrict__ out,
                                                       const float* __restrict__ W) {
  const float* wh = W + 2 * L_TOT + 1024;
  int tid = threadIdx.x;
  int t = (blockIdx.x == 0) ? tid : (OUTN - 256 + tid);
  int p = t + 512;
  int jmin = max(0, (p - 768) >> 8);
  int jmax = min(NFR - 1, p >> 8);
  float wsq = 0.0f;
  for (int j = jmin; j <= jmax; ++j) {
    float w = wh[p - 256 * j];
    wsq += w * w;
  }
  out[t] = out[t] * (1.5f / fmaxf(wsq, 1e-11f));
}

extern "C" void kernel_launch(void* const* d_in, const int* in_sizes, int n_in,
                              void* d_out, int out_size, void* d_ws, size_t ws_size,
                              hipStream_t stream) {
  const float* logf0 = (const float*)d_in[0];
  const float* envn  = (const float*)d_in[1];
  const float* envp  = (const float*)d_in[2];
  const float* noise = (const float*)d_in[3];
  float* out = (float*)d_out;
  float* W = (float*)d_ws;

  init_tables<<<dim3(72), dim3(256), 0, stream>>>(logf0, W);
  tree_kernel<<<dim3(2048), dim3(256), 0, stream>>>(W);
  tree_top_kernel<<<dim3(1), dim3(256), 0, stream>>>(W);
  pulse_kernel<<<dim3(L_TOT / 4096), dim3(256), 0, stream>>>(W);
  hipMemsetAsync(d_out, 0, (size_t)out_size * sizeof(float), stream);
  column_kernel<<<dim3(NFR / 2), dim3(256), 0, stream>>>(noise, envn, envp, W, out);
  finalize_kernel<<<dim3(2), dim3(256), 0, stream>>>(out, W);
}